// Round 14
// baseline (57.224 us; speedup 1.0000x reference)
//
#include <hip/hip_runtime.h>
#include <hip/hip_cooperative_groups.h>
#include <math.h>

namespace cg = cooperative_groups;

#define DN 16
#define DOUT 8
#define DH 32
#define DB 16384
#define RINV 10.0f
#define NBLK 256  // 256 blocks x 4 waves x 16 samples = 16384; <= 256 CUs -> co-resident

typedef __attribute__((ext_vector_type(4))) float f4;
typedef __attribute__((ext_vector_type(4))) _Float16 h4;

__device__ __forceinline__ f4 mfma(h4 a, h4 b, f4 c) {
  return __builtin_amdgcn_mfma_f32_16x16x16f16(a, b, c, 0, 0, 0);
}
__device__ __forceinline__ unsigned pk2(float a, float b) {
  return __builtin_bit_cast(unsigned, __builtin_amdgcn_cvt_pkrtz(a, b));
}
__device__ __forceinline__ h4 mkh4(f4 c) {
  uint2 u; u.x = pk2(c.x, c.y); u.y = pk2(c.z, c.w);
  return __builtin_bit_cast(h4, u);
}
__device__ __forceinline__ float ftanh(float v) {
  float ex = __builtin_amdgcn_exp2f(v * 2.885390081777926815f);
  float r = __builtin_amdgcn_rcpf(1.0f + ex);
  return fmaf(-2.0f, r, 1.0f);
}
__device__ __forceinline__ f4 tanh4(f4 v) {
  f4 r; r.x = ftanh(v.x); r.y = ftanh(v.y); r.z = ftanh(v.z); r.w = ftanh(v.w);
  return r;
}

// Fragment layouts for mfma_f32_16x16x16_f16 (lane l, j=0..3):
//   A: row = l&15,        k   = 4*(l>>4)+j
//   B: col = l&15,        k   = 4*(l>>4)+j
//   C/D: col = l&15,      row = 4*(l>>4)+j   [verified m89]
// => C/D layout == B layout: tanh'd outputs feed the next MFMA directly.

__global__ __launch_bounds__(256, 1) void loss_kernel(
    const float* __restrict__ x_batch, const float* __restrict__ e_batch,
    const float* __restrict__ Wf1, const float* __restrict__ bf1, const float* __restrict__ Wf2,
    const float* __restrict__ Wh1, const float* __restrict__ bh1, const float* __restrict__ Wh2,
    const float* __restrict__ WT1, const float* __restrict__ bT1, const float* __restrict__ WT2,
    const float* __restrict__ Wtau1, const float* __restrict__ btau1, const float* __restrict__ Wtau2,
    const float* __restrict__ Wpsi1, const float* __restrict__ bpsi1, const float* __restrict__ Wpsi2,
    const float* __restrict__ WP,
    float* __restrict__ part, float* __restrict__ out) {
  __shared__ float wsum[4];
  const int tid = threadIdx.x;
  const int l = tid & 63;
  const int r = l & 15, g = l >> 4;
  const int wid = blockIdx.x * 4 + (tid >> 6);
  const int s0 = wid * 16;
  const f4 zf = {0.f, 0.f, 0.f, 0.f};
  const f4 one = {1.f, 1.f, 1.f, 1.f};

  // ---- weight A-fragments (registers; identical across waves -> L2 broadcast) ----
  h4 A_T1[2], A_T2[2], A_tau1[2], A_tau2[2], A_h1[2], A_h2[2];
  h4 A_ps1a[2], A_ps1b[2], A_psi2[2], A_f1[2], A_f2[2], A_WP;
  h4 A_h1T[2], A_h2T[2];
#pragma unroll
  for (int mt = 0; mt < 2; ++mt) {  // M-tiles (rows r+16*mt) of 32xK row-major
    A_T1[mt]   = mkh4(*(const f4*)(WT1   + (r + 16 * mt) * DN + 4 * g));
    A_tau1[mt] = mkh4(*(const f4*)(Wtau1 + (r + 16 * mt) * DN + 4 * g));
    A_h1[mt]   = mkh4(*(const f4*)(Wh1   + (r + 16 * mt) * DN + 4 * g));
    A_f1[mt]   = mkh4(*(const f4*)(Wf1   + (r + 16 * mt) * DN + 4 * g));
    // psi1 (32x24): kt0 = cols 0..15 ; kt1 = cols 16..23 (k>=8 zero)
    A_ps1a[mt] = mkh4(*(const f4*)(Wpsi1 + (r + 16 * mt) * 24 + 4 * g));
    A_ps1b[mt] = (g < 2) ? mkh4(*(const f4*)(Wpsi1 + (r + 16 * mt) * 24 + 16 + 4 * g))
                         : mkh4(zf);
    // h2T (32x8): A[m][k] = Wh2[k][m], m = r+16mt, k = 4g+j < 8
    f4 t = zf;
    if (g < 2) {
      t.x = Wh2[(4 * g + 0) * DH + r + 16 * mt];
      t.y = Wh2[(4 * g + 1) * DH + r + 16 * mt];
      t.z = Wh2[(4 * g + 2) * DH + r + 16 * mt];
      t.w = Wh2[(4 * g + 3) * DH + r + 16 * mt];
    }
    A_h2T[mt] = mkh4(t);
  }
#pragma unroll
  for (int kt = 0; kt < 2; ++kt) {  // K-tiles of 16x32 row-major (row r, cols kt*16+4g..)
    A_T2[kt]   = mkh4(*(const f4*)(WT2   + r * DH + 16 * kt + 4 * g));
    A_tau2[kt] = mkh4(*(const f4*)(Wtau2 + r * DH + 16 * kt + 4 * g));
    A_psi2[kt] = mkh4(*(const f4*)(Wpsi2 + r * DH + 16 * kt + 4 * g));
    A_f2[kt]   = mkh4(*(const f4*)(Wf2   + r * DH + 16 * kt + 4 * g));
    // h2 (8x32 as A, M=16 pad rows>=8): A[m][k] = Wh2[r][16kt+4g+j], r<8
    A_h2[kt] = (r < 8) ? mkh4(*(const f4*)(Wh2 + r * DH + 16 * kt + 4 * g)) : mkh4(zf);
    // h1T (16x32): A[m][k] = Wh1[16kt+4g+j][m]
    f4 t;
    t.x = Wh1[(16 * kt + 4 * g + 0) * DN + r];
    t.y = Wh1[(16 * kt + 4 * g + 1) * DN + r];
    t.z = Wh1[(16 * kt + 4 * g + 2) * DN + r];
    t.w = Wh1[(16 * kt + 4 * g + 3) * DN + r];
    A_h1T[kt] = mkh4(t);
  }
  A_WP = mkh4(*(const f4*)(WP + r * DN + 4 * g));

  // biases as C-format f4: lane adds b[4g+j (+16*mt)]
  f4 bT1v[2], btau1v[2], bh1v[2], bpsi1v[2], bf1v[2];
#pragma unroll
  for (int mt = 0; mt < 2; ++mt) {
    bT1v[mt]   = *(const f4*)(bT1   + 16 * mt + 4 * g);
    btau1v[mt] = *(const f4*)(btau1 + 16 * mt + 4 * g);
    bh1v[mt]   = *(const f4*)(bh1   + 16 * mt + 4 * g);
    bpsi1v[mt] = *(const f4*)(bpsi1 + 16 * mt + 4 * g);
    bf1v[mt]   = *(const f4*)(bf1   + 16 * mt + 4 * g);
  }

  // ---- sample tiles: B-frag load pattern == C-format addition pattern (16x16) ----
  f4 xC = *(const f4*)(x_batch + (size_t)(s0 + r) * DN + 4 * g);
  f4 eC = *(const f4*)(e_batch + (size_t)(s0 + r) * DN + 4 * g);
  h4 xB = mkh4(xC), eB = mkh4(eC);

  // ---- A: z = T2 @ tanh(T1@x + b) + e ----
  f4 c0 = mfma(A_T1[0], xB, zf);
  f4 c1 = mfma(A_T1[1], xB, zf);
  h4 h0 = mkh4(tanh4(c0 + bT1v[0]));
  h4 h1 = mkh4(tanh4(c1 + bT1v[1]));
  f4 zc = mfma(A_T2[0], h0, zf);
  zc = mfma(A_T2[1], h1, zc);
  zc += eC;
  h4 zB = mkh4(zc);

  // ---- B: xh = tau(z); diff = x - xh ----
  c0 = mfma(A_tau1[0], zB, zf);
  c1 = mfma(A_tau1[1], zB, zf);
  h0 = mkh4(tanh4(c0 + btau1v[0]));
  h1 = mkh4(tanh4(c1 + btau1v[1]));
  f4 xhC = mfma(A_tau2[0], h0, zf);
  xhC = mfma(A_tau2[1], h1, xhC);
  h4 xhB = mkh4(xhC);
  h4 dfB = mkh4(xC - xhC);

  // ---- C: th, dth, yh ----
  c0 = mfma(A_h1[0], xhB, zf);
  c1 = mfma(A_h1[1], xhB, zf);
  f4 th0 = tanh4(c0 + bh1v[0]), th1 = tanh4(c1 + bh1v[1]);
  f4 dth0 = one - th0 * th0, dth1 = one - th1 * th1;
  f4 yhC = mfma(A_h2[0], mkh4(th0), zf);
  yhC = mfma(A_h2[1], mkh4(th1), yhC);  // rows 8..15 zero (A_h2 padded)
  h4 yhB = mkh4(yhC);

  // ---- D: w8 = RINV * Wh2 @ (dth o (Wh1 @ diff)) ----
  c0 = mfma(A_h1[0], dfB, zf);
  c1 = mfma(A_h1[1], dfB, zf);
  f4 w8C = mfma(A_h2[0], mkh4(dth0 * c0), zf);
  w8C = mfma(A_h2[1], mkh4(dth1 * c1), w8C);
  w8C *= RINV;
  h4 w8B = mkh4(w8C);  // k rows 8..15 zero

  // ---- E: u = Wh1^T @ (dth o (Wh2^T @ w8)) ----
  c0 = mfma(A_h2T[0], w8B, zf);
  c1 = mfma(A_h2T[1], w8B, zf);
  f4 uC = mfma(A_h1T[0], mkh4(dth0 * c0), zf);
  uC = mfma(A_h1T[1], mkh4(dth1 * c1), uC);

  // ---- F: s = tanh(WP@xh); term1 = u + s*(s.u) ----
  f4 svC = tanh4(mfma(A_WP, xhB, zf));
  float sd = svC.x * uC.x + svC.y * uC.y + svC.z * uC.z + svC.w * uC.w;
  sd += __shfl_xor(sd, 16);
  sd += __shfl_xor(sd, 32);
  f4 term1 = uC + svC * sd;

  // ---- G: Tx = T(xh) ----
  c0 = mfma(A_T1[0], xhB, zf);
  c1 = mfma(A_T1[1], xhB, zf);
  h0 = mkh4(tanh4(c0 + bT1v[0]));
  h1 = mkh4(tanh4(c1 + bT1v[1]));
  f4 TxC = mfma(A_T2[0], h0, zf);
  TxC = mfma(A_T2[1], h1, TxC);
  h4 TxB = mkh4(TxC);

  // ---- H: phi = psi(Tx,yh); jph = Jphi @ e ----
  c0 = mfma(A_ps1a[0], TxB, zf);
  c0 = mfma(A_ps1b[0], yhB, c0);
  c1 = mfma(A_ps1a[1], TxB, zf);
  c1 = mfma(A_ps1b[1], yhB, c1);
  f4 tp0 = tanh4(c0 + bpsi1v[0]), tp1 = tanh4(c1 + bpsi1v[1]);
  f4 dtp0 = one - tp0 * tp0, dtp1 = one - tp1 * tp1;
  f4 phiC = mfma(A_psi2[0], mkh4(tp0), zf);
  phiC = mfma(A_psi2[1], mkh4(tp1), phiC);
  h4 phiB = mkh4(phiC);
  c0 = mfma(A_ps1a[0], eB, zf);
  c1 = mfma(A_ps1a[1], eB, zf);
  f4 jphC = mfma(A_psi2[0], mkh4(dtp0 * c0), zf);
  jphC = mfma(A_psi2[1], mkh4(dtp1 * c1), jphC);
  h4 jphB = mkh4(jphC);

  // ---- I: t2e = Htau@e + Jtau@jph ; jte = Jtau@e ----
  f4 a0 = mfma(A_tau1[0], TxB, zf) + btau1v[0];
  f4 a1 = mfma(A_tau1[1], TxB, zf) + btau1v[1];
  f4 wp0 = mfma(A_tau1[0], phiB, zf), wp1 = mfma(A_tau1[1], phiB, zf);
  f4 vv0 = mfma(A_tau1[0], eB, zf), vv1 = mfma(A_tau1[1], eB, zf);
  f4 qq0 = mfma(A_tau1[0], jphB, zf), qq1 = mfma(A_tau1[1], jphB, zf);
  f4 t0 = tanh4(a0), t1 = tanh4(a1);
  f4 d0 = one - t0 * t0, d1 = one - t1 * t1;
  f4 cc0 = -2.0f * t0 * d0 * wp0, cc1 = -2.0f * t1 * d1 * wp1;
  f4 g1_0 = cc0 * vv0 + d0 * qq0, g1_1 = cc1 * vv1 + d1 * qq1;
  f4 g2_0 = d0 * vv0, g2_1 = d1 * vv1;
  f4 t2eC = mfma(A_tau2[0], mkh4(g1_0), zf);
  t2eC = mfma(A_tau2[1], mkh4(g1_1), t2eC);
  f4 jteC = mfma(A_tau2[0], mkh4(g2_0), zf);
  jteC = mfma(A_tau2[1], mkh4(g2_1), jteC);
  h4 jteB = mkh4(jteC);

  // ---- J: t2e -= Wf2 @ ((1-t^2) o (Wf1 @ jte)) ----
  a0 = mfma(A_f1[0], xhB, zf) + bf1v[0];
  a1 = mfma(A_f1[1], xhB, zf) + bf1v[1];
  f4 gj0 = mfma(A_f1[0], jteB, zf), gj1 = mfma(A_f1[1], jteB, zf);
  t0 = tanh4(a0);
  t1 = tanh4(a1);
  f4 gf0 = (one - t0 * t0) * gj0, gf1 = (one - t1 * t1) * gj1;
  f4 fC = mfma(A_f2[0], mkh4(gf0), zf);
  fC = mfma(A_f2[1], mkh4(gf1), fC);
  t2eC -= fC;

  // ---- K: loss ----
  f4 rr = term1 - t2eC;
  float ss = rr.x * rr.x + rr.y * rr.y + rr.z * rr.z + rr.w * rr.w;
  ss += __shfl_xor(ss, 16);
  ss += __shfl_xor(ss, 32);
  // ss now = per-column sum over all 16 rows; identical across the 4 row-groups
  float loss = sqrtf(ss) * 0.25f;  // each column counted 4x in the wave-sum below
#pragma unroll
  for (int off = 1; off < 64; off <<= 1) loss += __shfl_xor(loss, off);

  if (l == 0) wsum[tid >> 6] = loss;
  __syncthreads();
  if (tid == 0) part[blockIdx.x] = wsum[0] + wsum[1] + wsum[2] + wsum[3];
  __threadfence();  // release partials device-wide before grid sync

  // ---- grid-wide sync; block 0 finishes the reduction (no 2nd launch) ----
  cg::this_grid().sync();
  if (blockIdx.x == 0) {
    // device-coherent read (atomic RMW of +0) sidesteps any stale-L2 concern
    float v = atomicAdd(&part[tid], 0.0f);
#pragma unroll
    for (int off = 1; off < 64; off <<= 1) v += __shfl_xor(v, off);
    if (l == 0) wsum[tid >> 6] = v;
    __syncthreads();
    if (tid == 0)
      out[0] = (wsum[0] + wsum[1] + wsum[2] + wsum[3]) * (1.0f / (float)DB);
  }
}

extern "C" void kernel_launch(void* const* d_in, const int* in_sizes, int n_in,
                              void* d_out, int out_size, void* d_ws, size_t ws_size,
                              hipStream_t stream) {
  const float* x_batch = (const float*)d_in[0];
  const float* e_batch = (const float*)d_in[1];
  const float* Wf1 = (const float*)d_in[2];
  const float* bf1 = (const float*)d_in[3];
  const float* Wf2 = (const float*)d_in[4];
  const float* Wh1 = (const float*)d_in[5];
  const float* bh1 = (const float*)d_in[6];
  const float* Wh2 = (const float*)d_in[7];
  const float* WT1 = (const float*)d_in[8];
  const float* bT1 = (const float*)d_in[9];
  const float* WT2 = (const float*)d_in[10];
  const float* Wtau1 = (const float*)d_in[11];
  const float* btau1 = (const float*)d_in[12];
  const float* Wtau2 = (const float*)d_in[13];
  const float* Wpsi1 = (const float*)d_in[14];
  const float* bpsi1 = (const float*)d_in[15];
  const float* Wpsi2 = (const float*)d_in[16];
  const float* WP = (const float*)d_in[17];

  float* part = (float*)d_ws;   // NBLK floats, fully rewritten every call
  float* outp = (float*)d_out;

  void* args[] = {
      (void*)&x_batch, (void*)&e_batch,
      (void*)&Wf1, (void*)&bf1, (void*)&Wf2,
      (void*)&Wh1, (void*)&bh1, (void*)&Wh2,
      (void*)&WT1, (void*)&bT1, (void*)&WT2,
      (void*)&Wtau1, (void*)&btau1, (void*)&Wtau2,
      (void*)&Wpsi1, (void*)&bpsi1, (void*)&Wpsi2,
      (void*)&WP, (void*)&part, (void*)&outp};
  hipLaunchCooperativeKernel((const void*)loss_kernel, dim3(NBLK), dim3(256),
                             args, 0, stream);
}

// Round 15
// 20.726 us; speedup vs baseline: 2.7609x; 2.7609x over previous
//
#include <hip/hip_runtime.h>
#include <math.h>

#define DN 16
#define DOUT 8
#define DH 32
#define DB 16384
#define RINV 10.0f
#define NBLK 256  // 256 blocks x 4 waves x 16 samples = 16384

typedef __attribute__((ext_vector_type(4))) float f4;
typedef __attribute__((ext_vector_type(4))) _Float16 h4;

__device__ __forceinline__ f4 mfma(h4 a, h4 b, f4 c) {
  return __builtin_amdgcn_mfma_f32_16x16x16f16(a, b, c, 0, 0, 0);
}
__device__ __forceinline__ unsigned pk2(float a, float b) {
  return __builtin_bit_cast(unsigned, __builtin_amdgcn_cvt_pkrtz(a, b));
}
__device__ __forceinline__ h4 mkh4(f4 c) {
  uint2 u; u.x = pk2(c.x, c.y); u.y = pk2(c.z, c.w);
  return __builtin_bit_cast(h4, u);
}
__device__ __forceinline__ float ftanh(float v) {
  float ex = __builtin_amdgcn_exp2f(v * 2.885390081777926815f);
  float r = __builtin_amdgcn_rcpf(1.0f + ex);
  return fmaf(-2.0f, r, 1.0f);
}
__device__ __forceinline__ f4 tanh4(f4 v) {
  f4 r; r.x = ftanh(v.x); r.y = ftanh(v.y); r.z = ftanh(v.z); r.w = ftanh(v.w);
  return r;
}

// Fragment layouts for mfma_f32_16x16x16_f16 (lane l, j=0..3):
//   A: row = l&15,   k   = 4*(l>>4)+j
//   B: col = l&15,   k   = 4*(l>>4)+j
//   C/D: col = l&15, row = 4*(l>>4)+j   [verified m89]
// => C/D layout == B layout: tanh'd outputs feed the next MFMA directly.

__global__ __launch_bounds__(256, 1) void loss_kernel(
    const float* __restrict__ x_batch, const float* __restrict__ e_batch,
    const float* __restrict__ Wf1, const float* __restrict__ bf1, const float* __restrict__ Wf2,
    const float* __restrict__ Wh1, const float* __restrict__ bh1, const float* __restrict__ Wh2,
    const float* __restrict__ WT1, const float* __restrict__ bT1, const float* __restrict__ WT2,
    const float* __restrict__ Wtau1, const float* __restrict__ btau1, const float* __restrict__ Wtau2,
    const float* __restrict__ Wpsi1, const float* __restrict__ bpsi1, const float* __restrict__ Wpsi2,
    const float* __restrict__ WP,
    float* __restrict__ part, unsigned* __restrict__ counter, float* __restrict__ out) {
  __shared__ float wsum[4];
  __shared__ unsigned ticket;
  const int tid = threadIdx.x;
  const int l = tid & 63;
  const int r = l & 15, g = l >> 4;
  const int wid = blockIdx.x * 4 + (tid >> 6);
  const int s0 = wid * 16;
  const f4 zf = {0.f, 0.f, 0.f, 0.f};
  const f4 one = {1.f, 1.f, 1.f, 1.f};

  // ---- weight A-fragments (registers; identical across waves -> L2 broadcast) ----
  h4 A_T1[2], A_T2[2], A_tau1[2], A_tau2[2], A_h1[2], A_h2[2];
  h4 A_ps1a[2], A_ps1b[2], A_psi2[2], A_f1[2], A_f2[2], A_WP;
  h4 A_h1T[2], A_h2T[2];
#pragma unroll
  for (int mt = 0; mt < 2; ++mt) {  // M-tiles (rows r+16*mt) of 32xK row-major
    A_T1[mt]   = mkh4(*(const f4*)(WT1   + (r + 16 * mt) * DN + 4 * g));
    A_tau1[mt] = mkh4(*(const f4*)(Wtau1 + (r + 16 * mt) * DN + 4 * g));
    A_h1[mt]   = mkh4(*(const f4*)(Wh1   + (r + 16 * mt) * DN + 4 * g));
    A_f1[mt]   = mkh4(*(const f4*)(Wf1   + (r + 16 * mt) * DN + 4 * g));
    // psi1 (32x24): kt0 = cols 0..15 ; kt1 = cols 16..23 (k>=8 zero)
    A_ps1a[mt] = mkh4(*(const f4*)(Wpsi1 + (r + 16 * mt) * 24 + 4 * g));
    A_ps1b[mt] = (g < 2) ? mkh4(*(const f4*)(Wpsi1 + (r + 16 * mt) * 24 + 16 + 4 * g))
                         : mkh4(zf);
    // h2T (32x8): A[m][k] = Wh2[k][m], m = r+16mt, k = 4g+j < 8
    f4 t = zf;
    if (g < 2) {
      t.x = Wh2[(4 * g + 0) * DH + r + 16 * mt];
      t.y = Wh2[(4 * g + 1) * DH + r + 16 * mt];
      t.z = Wh2[(4 * g + 2) * DH + r + 16 * mt];
      t.w = Wh2[(4 * g + 3) * DH + r + 16 * mt];
    }
    A_h2T[mt] = mkh4(t);
  }
#pragma unroll
  for (int kt = 0; kt < 2; ++kt) {  // K-tiles of 16x32 row-major (row r, cols kt*16+4g..)
    A_T2[kt]   = mkh4(*(const f4*)(WT2   + r * DH + 16 * kt + 4 * g));
    A_tau2[kt] = mkh4(*(const f4*)(Wtau2 + r * DH + 16 * kt + 4 * g));
    A_psi2[kt] = mkh4(*(const f4*)(Wpsi2 + r * DH + 16 * kt + 4 * g));
    A_f2[kt]   = mkh4(*(const f4*)(Wf2   + r * DH + 16 * kt + 4 * g));
    // h2 (8x32 as A, M=16 pad rows>=8): A[m][k] = Wh2[r][16kt+4g+j], r<8
    A_h2[kt] = (r < 8) ? mkh4(*(const f4*)(Wh2 + r * DH + 16 * kt + 4 * g)) : mkh4(zf);
    // h1T (16x32): A[m][k] = Wh1[16kt+4g+j][m]
    f4 t;
    t.x = Wh1[(16 * kt + 4 * g + 0) * DN + r];
    t.y = Wh1[(16 * kt + 4 * g + 1) * DN + r];
    t.z = Wh1[(16 * kt + 4 * g + 2) * DN + r];
    t.w = Wh1[(16 * kt + 4 * g + 3) * DN + r];
    A_h1T[kt] = mkh4(t);
  }
  A_WP = mkh4(*(const f4*)(WP + r * DN + 4 * g));

  // biases as C-format f4: lane adds b[4g+j (+16*mt)]
  f4 bT1v[2], btau1v[2], bh1v[2], bpsi1v[2], bf1v[2];
#pragma unroll
  for (int mt = 0; mt < 2; ++mt) {
    bT1v[mt]   = *(const f4*)(bT1   + 16 * mt + 4 * g);
    btau1v[mt] = *(const f4*)(btau1 + 16 * mt + 4 * g);
    bh1v[mt]   = *(const f4*)(bh1   + 16 * mt + 4 * g);
    bpsi1v[mt] = *(const f4*)(bpsi1 + 16 * mt + 4 * g);
    bf1v[mt]   = *(const f4*)(bf1   + 16 * mt + 4 * g);
  }

  // ---- sample tiles: B-frag load pattern == C-format addition pattern (16x16) ----
  f4 xC = *(const f4*)(x_batch + (size_t)(s0 + r) * DN + 4 * g);
  f4 eC = *(const f4*)(e_batch + (size_t)(s0 + r) * DN + 4 * g);
  h4 xB = mkh4(xC), eB = mkh4(eC);

  // ---- A: z = T2 @ tanh(T1@x + b) + e ----
  f4 c0 = mfma(A_T1[0], xB, zf);
  f4 c1 = mfma(A_T1[1], xB, zf);
  h4 h0 = mkh4(tanh4(c0 + bT1v[0]));
  h4 h1 = mkh4(tanh4(c1 + bT1v[1]));
  f4 zc = mfma(A_T2[0], h0, zf);
  zc = mfma(A_T2[1], h1, zc);
  zc += eC;
  h4 zB = mkh4(zc);

  // ---- B: xh = tau(z); diff = x - xh ----
  c0 = mfma(A_tau1[0], zB, zf);
  c1 = mfma(A_tau1[1], zB, zf);
  h0 = mkh4(tanh4(c0 + btau1v[0]));
  h1 = mkh4(tanh4(c1 + btau1v[1]));
  f4 xhC = mfma(A_tau2[0], h0, zf);
  xhC = mfma(A_tau2[1], h1, xhC);
  h4 xhB = mkh4(xhC);
  h4 dfB = mkh4(xC - xhC);

  // ---- C: th, dth, yh ----
  c0 = mfma(A_h1[0], xhB, zf);
  c1 = mfma(A_h1[1], xhB, zf);
  f4 th0 = tanh4(c0 + bh1v[0]), th1 = tanh4(c1 + bh1v[1]);
  f4 dth0 = one - th0 * th0, dth1 = one - th1 * th1;
  f4 yhC = mfma(A_h2[0], mkh4(th0), zf);
  yhC = mfma(A_h2[1], mkh4(th1), yhC);  // rows 8..15 zero (A_h2 padded)
  h4 yhB = mkh4(yhC);

  // ---- D: w8 = RINV * Wh2 @ (dth o (Wh1 @ diff)) ----
  c0 = mfma(A_h1[0], dfB, zf);
  c1 = mfma(A_h1[1], dfB, zf);
  f4 w8C = mfma(A_h2[0], mkh4(dth0 * c0), zf);
  w8C = mfma(A_h2[1], mkh4(dth1 * c1), w8C);
  w8C *= RINV;
  h4 w8B = mkh4(w8C);  // k rows 8..15 zero

  // ---- E: u = Wh1^T @ (dth o (Wh2^T @ w8)) ----
  c0 = mfma(A_h2T[0], w8B, zf);
  c1 = mfma(A_h2T[1], w8B, zf);
  f4 uC = mfma(A_h1T[0], mkh4(dth0 * c0), zf);
  uC = mfma(A_h1T[1], mkh4(dth1 * c1), uC);

  // ---- F: s = tanh(WP@xh); term1 = u + s*(s.u) ----
  f4 svC = tanh4(mfma(A_WP, xhB, zf));
  float sd = svC.x * uC.x + svC.y * uC.y + svC.z * uC.z + svC.w * uC.w;
  sd += __shfl_xor(sd, 16);
  sd += __shfl_xor(sd, 32);
  f4 term1 = uC + svC * sd;

  // ---- G: Tx = T(xh) ----
  c0 = mfma(A_T1[0], xhB, zf);
  c1 = mfma(A_T1[1], xhB, zf);
  h0 = mkh4(tanh4(c0 + bT1v[0]));
  h1 = mkh4(tanh4(c1 + bT1v[1]));
  f4 TxC = mfma(A_T2[0], h0, zf);
  TxC = mfma(A_T2[1], h1, TxC);
  h4 TxB = mkh4(TxC);

  // ---- H: phi = psi(Tx,yh); jph = Jphi @ e ----
  c0 = mfma(A_ps1a[0], TxB, zf);
  c0 = mfma(A_ps1b[0], yhB, c0);
  c1 = mfma(A_ps1a[1], TxB, zf);
  c1 = mfma(A_ps1b[1], yhB, c1);
  f4 tp0 = tanh4(c0 + bpsi1v[0]), tp1 = tanh4(c1 + bpsi1v[1]);
  f4 dtp0 = one - tp0 * tp0, dtp1 = one - tp1 * tp1;
  f4 phiC = mfma(A_psi2[0], mkh4(tp0), zf);
  phiC = mfma(A_psi2[1], mkh4(tp1), phiC);
  h4 phiB = mkh4(phiC);
  c0 = mfma(A_ps1a[0], eB, zf);
  c1 = mfma(A_ps1a[1], eB, zf);
  f4 jphC = mfma(A_psi2[0], mkh4(dtp0 * c0), zf);
  jphC = mfma(A_psi2[1], mkh4(dtp1 * c1), jphC);
  h4 jphB = mkh4(jphC);

  // ---- I: t2e = Htau@e + Jtau@jph ; jte = Jtau@e ----
  f4 a0 = mfma(A_tau1[0], TxB, zf) + btau1v[0];
  f4 a1 = mfma(A_tau1[1], TxB, zf) + btau1v[1];
  f4 wp0 = mfma(A_tau1[0], phiB, zf), wp1 = mfma(A_tau1[1], phiB, zf);
  f4 vv0 = mfma(A_tau1[0], eB, zf), vv1 = mfma(A_tau1[1], eB, zf);
  f4 qq0 = mfma(A_tau1[0], jphB, zf), qq1 = mfma(A_tau1[1], jphB, zf);
  f4 t0 = tanh4(a0), t1 = tanh4(a1);
  f4 d0 = one - t0 * t0, d1 = one - t1 * t1;
  f4 cc0 = -2.0f * t0 * d0 * wp0, cc1 = -2.0f * t1 * d1 * wp1;
  f4 g1_0 = cc0 * vv0 + d0 * qq0, g1_1 = cc1 * vv1 + d1 * qq1;
  f4 g2_0 = d0 * vv0, g2_1 = d1 * vv1;
  f4 t2eC = mfma(A_tau2[0], mkh4(g1_0), zf);
  t2eC = mfma(A_tau2[1], mkh4(g1_1), t2eC);
  f4 jteC = mfma(A_tau2[0], mkh4(g2_0), zf);
  jteC = mfma(A_tau2[1], mkh4(g2_1), jteC);
  h4 jteB = mkh4(jteC);

  // ---- J: t2e -= Wf2 @ ((1-t^2) o (Wf1 @ jte)) ----
  a0 = mfma(A_f1[0], xhB, zf) + bf1v[0];
  a1 = mfma(A_f1[1], xhB, zf) + bf1v[1];
  f4 gj0 = mfma(A_f1[0], jteB, zf), gj1 = mfma(A_f1[1], jteB, zf);
  t0 = tanh4(a0);
  t1 = tanh4(a1);
  f4 gf0 = (one - t0 * t0) * gj0, gf1 = (one - t1 * t1) * gj1;
  f4 fC = mfma(A_f2[0], mkh4(gf0), zf);
  fC = mfma(A_f2[1], mkh4(gf1), fC);
  t2eC -= fC;

  // ---- K: loss ----
  f4 rr = term1 - t2eC;
  float ss = rr.x * rr.x + rr.y * rr.y + rr.z * rr.z + rr.w * rr.w;
  ss += __shfl_xor(ss, 16);
  ss += __shfl_xor(ss, 32);
  // ss now = per-column sum over all 16 rows; identical across the 4 row-groups
  float loss = sqrtf(ss) * 0.25f;  // each column counted 4x in the wave-sum below
#pragma unroll
  for (int off = 1; off < 64; off <<= 1) loss += __shfl_xor(loss, off);

  if (l == 0) wsum[tid >> 6] = loss;
  __syncthreads();
  if (tid == 0) {
    part[blockIdx.x] = wsum[0] + wsum[1] + wsum[2] + wsum[3];
    __threadfence();  // make the partial device-visible BEFORE taking a ticket
    ticket = atomicAdd(counter, 1u);
  }
  __syncthreads();

  // ---- last block to finish reduces all partials (single dispatch, no grid sync) ----
  if (ticket == NBLK - 1) {
    // device-coherent read (atomic RMW of +0) sidesteps any stale-L1/L2 concern
    float v = atomicAdd(&part[tid], 0.0f);  // 256 threads <-> 256 partials
#pragma unroll
    for (int off = 1; off < 64; off <<= 1) v += __shfl_xor(v, off);
    __syncthreads();  // guard wsum reuse (WAR with the reads above)
    if (l == 0) wsum[tid >> 6] = v;
    __syncthreads();
    if (tid == 0)
      out[0] = (wsum[0] + wsum[1] + wsum[2] + wsum[3]) * (1.0f / (float)DB);
  }
}

extern "C" void kernel_launch(void* const* d_in, const int* in_sizes, int n_in,
                              void* d_out, int out_size, void* d_ws, size_t ws_size,
                              hipStream_t stream) {
  const float* x_batch = (const float*)d_in[0];
  const float* e_batch = (const float*)d_in[1];
  const float* Wf1 = (const float*)d_in[2];
  const float* bf1 = (const float*)d_in[3];
  const float* Wf2 = (const float*)d_in[4];
  const float* Wh1 = (const float*)d_in[5];
  const float* bh1 = (const float*)d_in[6];
  const float* Wh2 = (const float*)d_in[7];
  const float* WT1 = (const float*)d_in[8];
  const float* bT1 = (const float*)d_in[9];
  const float* WT2 = (const float*)d_in[10];
  const float* Wtau1 = (const float*)d_in[11];
  const float* btau1 = (const float*)d_in[12];
  const float* Wtau2 = (const float*)d_in[13];
  const float* Wpsi1 = (const float*)d_in[14];
  const float* bpsi1 = (const float*)d_in[15];
  const float* Wpsi2 = (const float*)d_in[16];
  const float* WP = (const float*)d_in[17];

  float* part = (float*)d_ws;                      // NBLK floats, rewritten every call
  unsigned* counter = (unsigned*)(part + NBLK);    // 1 uint, zeroed every call

  hipMemsetAsync(counter, 0, sizeof(unsigned), stream);
  loss_kernel<<<NBLK, 256, 0, stream>>>(
      x_batch, e_batch, Wf1, bf1, Wf2, Wh1, bh1, Wh2, WT1, bT1, WT2,
      Wtau1, btau1, Wtau2, Wpsi1, bpsi1, Wpsi2, WP, part, counter, (float*)d_out);
}

// Round 16
// 12.231 us; speedup vs baseline: 4.6786x; 1.6946x over previous
//
#include <hip/hip_runtime.h>
#include <math.h>

#define DN 16
#define DOUT 8
#define DH 32
#define DB 16384
#define RINV 10.0f
#define NBLK 256  // 256 blocks x 4 waves x 16 samples = 16384

typedef __attribute__((ext_vector_type(4))) float f4;
typedef __attribute__((ext_vector_type(4))) _Float16 h4;

__device__ __forceinline__ f4 mfma(h4 a, h4 b, f4 c) {
  return __builtin_amdgcn_mfma_f32_16x16x16f16(a, b, c, 0, 0, 0);
}
__device__ __forceinline__ unsigned pk2(float a, float b) {
  return __builtin_bit_cast(unsigned, __builtin_amdgcn_cvt_pkrtz(a, b));
}
__device__ __forceinline__ h4 mkh4(f4 c) {
  uint2 u; u.x = pk2(c.x, c.y); u.y = pk2(c.z, c.w);
  return __builtin_bit_cast(h4, u);
}
__device__ __forceinline__ float ftanh(float v) {
  float ex = __builtin_amdgcn_exp2f(v * 2.885390081777926815f);
  float r = __builtin_amdgcn_rcpf(1.0f + ex);
  return fmaf(-2.0f, r, 1.0f);
}
__device__ __forceinline__ f4 tanh4(f4 v) {
  f4 r; r.x = ftanh(v.x); r.y = ftanh(v.y); r.z = ftanh(v.z); r.w = ftanh(v.w);
  return r;
}

// Fragment layouts for mfma_f32_16x16x16_f16 (lane l, j=0..3):
//   A: row = l&15,        k   = 4*(l>>4)+j
//   B: col = l&15,        k   = 4*(l>>4)+j
//   C/D: col = l&15,      row = 4*(l>>4)+j   [verified m89]
// => C/D layout == B layout: tanh'd outputs feed the next MFMA directly.

__global__ __launch_bounds__(256, 1) void loss_kernel(
    const float* __restrict__ x_batch, const float* __restrict__ e_batch,
    const float* __restrict__ Wf1, const float* __restrict__ bf1, const float* __restrict__ Wf2,
    const float* __restrict__ Wh1, const float* __restrict__ bh1, const float* __restrict__ Wh2,
    const float* __restrict__ WT1, const float* __restrict__ bT1, const float* __restrict__ WT2,
    const float* __restrict__ Wtau1, const float* __restrict__ btau1, const float* __restrict__ Wtau2,
    const float* __restrict__ Wpsi1, const float* __restrict__ bpsi1, const float* __restrict__ Wpsi2,
    const float* __restrict__ WP,
    float* __restrict__ part) {
  __shared__ float wsum[4];
  const int tid = threadIdx.x;
  const int l = tid & 63;
  const int r = l & 15, g = l >> 4;
  const int wid = blockIdx.x * 4 + (tid >> 6);
  const int s0 = wid * 16;
  const f4 zf = {0.f, 0.f, 0.f, 0.f};
  const f4 one = {1.f, 1.f, 1.f, 1.f};

  // ---- weight A-fragments (registers; identical across waves -> L2 broadcast) ----
  h4 A_T1[2], A_T2[2], A_tau1[2], A_tau2[2], A_h1[2], A_h2[2];
  h4 A_ps1a[2], A_ps1b[2], A_psi2[2], A_f1[2], A_f2[2], A_WP;
  h4 A_h1T[2], A_h2T[2];
#pragma unroll
  for (int mt = 0; mt < 2; ++mt) {  // M-tiles (rows r+16*mt) of 32xK row-major
    A_T1[mt]   = mkh4(*(const f4*)(WT1   + (r + 16 * mt) * DN + 4 * g));
    A_tau1[mt] = mkh4(*(const f4*)(Wtau1 + (r + 16 * mt) * DN + 4 * g));
    A_h1[mt]   = mkh4(*(const f4*)(Wh1   + (r + 16 * mt) * DN + 4 * g));
    A_f1[mt]   = mkh4(*(const f4*)(Wf1   + (r + 16 * mt) * DN + 4 * g));
    // psi1 (32x24): kt0 = cols 0..15 ; kt1 = cols 16..23 (k>=8 zero)
    A_ps1a[mt] = mkh4(*(const f4*)(Wpsi1 + (r + 16 * mt) * 24 + 4 * g));
    A_ps1b[mt] = (g < 2) ? mkh4(*(const f4*)(Wpsi1 + (r + 16 * mt) * 24 + 16 + 4 * g))
                         : mkh4(zf);
    // h2T (32x8): A[m][k] = Wh2[k][m], m = r+16mt, k = 4g+j < 8
    f4 t = zf;
    if (g < 2) {
      t.x = Wh2[(4 * g + 0) * DH + r + 16 * mt];
      t.y = Wh2[(4 * g + 1) * DH + r + 16 * mt];
      t.z = Wh2[(4 * g + 2) * DH + r + 16 * mt];
      t.w = Wh2[(4 * g + 3) * DH + r + 16 * mt];
    }
    A_h2T[mt] = mkh4(t);
  }
#pragma unroll
  for (int kt = 0; kt < 2; ++kt) {  // K-tiles of 16x32 row-major (row r, cols kt*16+4g..)
    A_T2[kt]   = mkh4(*(const f4*)(WT2   + r * DH + 16 * kt + 4 * g));
    A_tau2[kt] = mkh4(*(const f4*)(Wtau2 + r * DH + 16 * kt + 4 * g));
    A_psi2[kt] = mkh4(*(const f4*)(Wpsi2 + r * DH + 16 * kt + 4 * g));
    A_f2[kt]   = mkh4(*(const f4*)(Wf2   + r * DH + 16 * kt + 4 * g));
    // h2 (8x32 as A, M=16 pad rows>=8): A[m][k] = Wh2[r][16kt+4g+j], r<8
    A_h2[kt] = (r < 8) ? mkh4(*(const f4*)(Wh2 + r * DH + 16 * kt + 4 * g)) : mkh4(zf);
    // h1T (16x32): A[m][k] = Wh1[16kt+4g+j][m]
    f4 t;
    t.x = Wh1[(16 * kt + 4 * g + 0) * DN + r];
    t.y = Wh1[(16 * kt + 4 * g + 1) * DN + r];
    t.z = Wh1[(16 * kt + 4 * g + 2) * DN + r];
    t.w = Wh1[(16 * kt + 4 * g + 3) * DN + r];
    A_h1T[kt] = mkh4(t);
  }
  A_WP = mkh4(*(const f4*)(WP + r * DN + 4 * g));

  // biases as C-format f4: lane adds b[4g+j (+16*mt)]
  f4 bT1v[2], btau1v[2], bh1v[2], bpsi1v[2], bf1v[2];
#pragma unroll
  for (int mt = 0; mt < 2; ++mt) {
    bT1v[mt]   = *(const f4*)(bT1   + 16 * mt + 4 * g);
    btau1v[mt] = *(const f4*)(btau1 + 16 * mt + 4 * g);
    bh1v[mt]   = *(const f4*)(bh1   + 16 * mt + 4 * g);
    bpsi1v[mt] = *(const f4*)(bpsi1 + 16 * mt + 4 * g);
    bf1v[mt]   = *(const f4*)(bf1   + 16 * mt + 4 * g);
  }

  // ---- sample tiles: B-frag load pattern == C-format addition pattern (16x16) ----
  f4 xC = *(const f4*)(x_batch + (size_t)(s0 + r) * DN + 4 * g);
  f4 eC = *(const f4*)(e_batch + (size_t)(s0 + r) * DN + 4 * g);
  h4 xB = mkh4(xC), eB = mkh4(eC);

  // ---- A: z = T2 @ tanh(T1@x + b) + e ----
  f4 c0 = mfma(A_T1[0], xB, zf);
  f4 c1 = mfma(A_T1[1], xB, zf);
  h4 h0 = mkh4(tanh4(c0 + bT1v[0]));
  h4 h1 = mkh4(tanh4(c1 + bT1v[1]));
  f4 zc = mfma(A_T2[0], h0, zf);
  zc = mfma(A_T2[1], h1, zc);
  zc += eC;
  h4 zB = mkh4(zc);

  // ---- B: xh = tau(z); diff = x - xh ----
  c0 = mfma(A_tau1[0], zB, zf);
  c1 = mfma(A_tau1[1], zB, zf);
  h0 = mkh4(tanh4(c0 + btau1v[0]));
  h1 = mkh4(tanh4(c1 + btau1v[1]));
  f4 xhC = mfma(A_tau2[0], h0, zf);
  xhC = mfma(A_tau2[1], h1, xhC);
  h4 xhB = mkh4(xhC);
  h4 dfB = mkh4(xC - xhC);

  // ---- C: th, dth, yh ----
  c0 = mfma(A_h1[0], xhB, zf);
  c1 = mfma(A_h1[1], xhB, zf);
  f4 th0 = tanh4(c0 + bh1v[0]), th1 = tanh4(c1 + bh1v[1]);
  f4 dth0 = one - th0 * th0, dth1 = one - th1 * th1;
  f4 yhC = mfma(A_h2[0], mkh4(th0), zf);
  yhC = mfma(A_h2[1], mkh4(th1), yhC);  // rows 8..15 zero (A_h2 padded)
  h4 yhB = mkh4(yhC);

  // ---- D: w8 = RINV * Wh2 @ (dth o (Wh1 @ diff)) ----
  c0 = mfma(A_h1[0], dfB, zf);
  c1 = mfma(A_h1[1], dfB, zf);
  f4 w8C = mfma(A_h2[0], mkh4(dth0 * c0), zf);
  w8C = mfma(A_h2[1], mkh4(dth1 * c1), w8C);
  w8C *= RINV;
  h4 w8B = mkh4(w8C);  // k rows 8..15 zero

  // ---- E: u = Wh1^T @ (dth o (Wh2^T @ w8)) ----
  c0 = mfma(A_h2T[0], w8B, zf);
  c1 = mfma(A_h2T[1], w8B, zf);
  f4 uC = mfma(A_h1T[0], mkh4(dth0 * c0), zf);
  uC = mfma(A_h1T[1], mkh4(dth1 * c1), uC);

  // ---- F: s = tanh(WP@xh); term1 = u + s*(s.u) ----
  f4 svC = tanh4(mfma(A_WP, xhB, zf));
  float sd = svC.x * uC.x + svC.y * uC.y + svC.z * uC.z + svC.w * uC.w;
  sd += __shfl_xor(sd, 16);
  sd += __shfl_xor(sd, 32);
  f4 term1 = uC + svC * sd;

  // ---- G: Tx = T(xh) ----
  c0 = mfma(A_T1[0], xhB, zf);
  c1 = mfma(A_T1[1], xhB, zf);
  h0 = mkh4(tanh4(c0 + bT1v[0]));
  h1 = mkh4(tanh4(c1 + bT1v[1]));
  f4 TxC = mfma(A_T2[0], h0, zf);
  TxC = mfma(A_T2[1], h1, TxC);
  h4 TxB = mkh4(TxC);

  // ---- H: phi = psi(Tx,yh); jph = Jphi @ e ----
  c0 = mfma(A_ps1a[0], TxB, zf);
  c0 = mfma(A_ps1b[0], yhB, c0);
  c1 = mfma(A_ps1a[1], TxB, zf);
  c1 = mfma(A_ps1b[1], yhB, c1);
  f4 tp0 = tanh4(c0 + bpsi1v[0]), tp1 = tanh4(c1 + bpsi1v[1]);
  f4 dtp0 = one - tp0 * tp0, dtp1 = one - tp1 * tp1;
  f4 phiC = mfma(A_psi2[0], mkh4(tp0), zf);
  phiC = mfma(A_psi2[1], mkh4(tp1), phiC);
  h4 phiB = mkh4(phiC);
  c0 = mfma(A_ps1a[0], eB, zf);
  c1 = mfma(A_ps1a[1], eB, zf);
  f4 jphC = mfma(A_psi2[0], mkh4(dtp0 * c0), zf);
  jphC = mfma(A_psi2[1], mkh4(dtp1 * c1), jphC);
  h4 jphB = mkh4(jphC);

  // ---- I: t2e = Htau@e + Jtau@jph ; jte = Jtau@e ----
  f4 a0 = mfma(A_tau1[0], TxB, zf) + btau1v[0];
  f4 a1 = mfma(A_tau1[1], TxB, zf) + btau1v[1];
  f4 wp0 = mfma(A_tau1[0], phiB, zf), wp1 = mfma(A_tau1[1], phiB, zf);
  f4 vv0 = mfma(A_tau1[0], eB, zf), vv1 = mfma(A_tau1[1], eB, zf);
  f4 qq0 = mfma(A_tau1[0], jphB, zf), qq1 = mfma(A_tau1[1], jphB, zf);
  f4 t0 = tanh4(a0), t1 = tanh4(a1);
  f4 d0 = one - t0 * t0, d1 = one - t1 * t1;
  f4 cc0 = -2.0f * t0 * d0 * wp0, cc1 = -2.0f * t1 * d1 * wp1;
  f4 g1_0 = cc0 * vv0 + d0 * qq0, g1_1 = cc1 * vv1 + d1 * qq1;
  f4 g2_0 = d0 * vv0, g2_1 = d1 * vv1;
  f4 t2eC = mfma(A_tau2[0], mkh4(g1_0), zf);
  t2eC = mfma(A_tau2[1], mkh4(g1_1), t2eC);
  f4 jteC = mfma(A_tau2[0], mkh4(g2_0), zf);
  jteC = mfma(A_tau2[1], mkh4(g2_1), jteC);
  h4 jteB = mkh4(jteC);

  // ---- J: t2e -= Wf2 @ ((1-t^2) o (Wf1 @ jte)) ----
  a0 = mfma(A_f1[0], xhB, zf) + bf1v[0];
  a1 = mfma(A_f1[1], xhB, zf) + bf1v[1];
  f4 gj0 = mfma(A_f1[0], jteB, zf), gj1 = mfma(A_f1[1], jteB, zf);
  t0 = tanh4(a0);
  t1 = tanh4(a1);
  f4 gf0 = (one - t0 * t0) * gj0, gf1 = (one - t1 * t1) * gj1;
  f4 fC = mfma(A_f2[0], mkh4(gf0), zf);
  fC = mfma(A_f2[1], mkh4(gf1), fC);
  t2eC -= fC;

  // ---- K: loss ----
  f4 rr = term1 - t2eC;
  float ss = rr.x * rr.x + rr.y * rr.y + rr.z * rr.z + rr.w * rr.w;
  ss += __shfl_xor(ss, 16);
  ss += __shfl_xor(ss, 32);
  // ss now = per-column sum over all 16 rows; identical across the 4 row-groups
  float loss = sqrtf(ss) * 0.25f;  // each column counted 4x in the wave-sum below
#pragma unroll
  for (int off = 1; off < 64; off <<= 1) loss += __shfl_xor(loss, off);

  if (l == 0) wsum[tid >> 6] = loss;
  __syncthreads();
  if (tid == 0) part[blockIdx.x] = wsum[0] + wsum[1] + wsum[2] + wsum[3];
}

// reduce 256 partials -> out[0]
__global__ __launch_bounds__(64, 1) void reduce_kernel(const float* __restrict__ part,
                                                       float* __restrict__ out) {
  const int tid = threadIdx.x;
  float v = part[tid] + part[tid + 64] + part[tid + 128] + part[tid + 192];
#pragma unroll
  for (int off = 1; off < 64; off <<= 1) v += __shfl_xor(v, off);
  if (tid == 0) out[0] = v * (1.0f / (float)DB);
}

extern "C" void kernel_launch(void* const* d_in, const int* in_sizes, int n_in,
                              void* d_out, int out_size, void* d_ws, size_t ws_size,
                              hipStream_t stream) {
  const float* x_batch = (const float*)d_in[0];
  const float* e_batch = (const float*)d_in[1];
  const float* Wf1 = (const float*)d_in[2];
  const float* bf1 = (const float*)d_in[3];
  const float* Wf2 = (const float*)d_in[4];
  const float* Wh1 = (const float*)d_in[5];
  const float* bh1 = (const float*)d_in[6];
  const float* Wh2 = (const float*)d_in[7];
  const float* WT1 = (const float*)d_in[8];
  const float* bT1 = (const float*)d_in[9];
  const float* WT2 = (const float*)d_in[10];
  const float* Wtau1 = (const float*)d_in[11];
  const float* btau1 = (const float*)d_in[12];
  const float* Wtau2 = (const float*)d_in[13];
  const float* Wpsi1 = (const float*)d_in[14];
  const float* bpsi1 = (const float*)d_in[15];
  const float* Wpsi2 = (const float*)d_in[16];
  const float* WP = (const float*)d_in[17];

  float* part = (float*)d_ws;  // NBLK floats, fully rewritten every call
  loss_kernel<<<NBLK, 256, 0, stream>>>(
      x_batch, e_batch, Wf1, bf1, Wf2, Wh1, bh1, Wh2, WT1, bT1, WT2,
      Wtau1, btau1, Wtau2, Wpsi1, bpsi1, Wpsi2, WP, part);
  reduce_kernel<<<1, 64, 0, stream>>>(part, (float*)d_out);
}